// Round 6
// baseline (564.925 us; speedup 1.0000x reference)
//
#include <hip/hip_runtime.h>
#include <math.h>

#define NBATCH 2
#define LQ     19560
#define LEN    19560
#define NQ     (NBATCH * LQ)      // 39120
#define DMODEL 256
#define NHEADS 8
#define HDIM   32
#define NLEV   4
#define NPTS   4
#define LDQS   384                // QS row stride: [0..255]=offsets, [256..383]=aw

typedef __bf16 bf16x8 __attribute__((ext_vector_type(8)));
typedef float  f32x4  __attribute__((ext_vector_type(4)));
typedef float  f32x2  __attribute__((ext_vector_type(2)));

__device__ inline float bf2f(unsigned short u) {
    return __uint_as_float(((unsigned int)u) << 16);
}
__device__ inline unsigned short f2bf(float f) {
    unsigned int u = __float_as_uint(f);
    u += 0x7FFFu + ((u >> 16) & 1u);     // RNE
    return (unsigned short)(u >> 16);
}
// two bf16 packed in a dword -> two exact f32 (lo = u<<16, hi = u & 0xFFFF0000)
__device__ inline f32x2 bfpair(unsigned int u) {
    f32x2 r;
    r.x = __uint_as_float(u << 16);
    r.y = __uint_as_float(u & 0xFFFF0000u);
    return r;
}

// ---------------------------------------------------------------------------
// Merged preprocessing (one dispatch, disjoint outputs):
//   b in [0,19560):        fp32->bf16 convert of q0/q1/f0/f1 (tsel=b/4890)
//   b in [19560,20200):    weight transpose/pack (Wvt, Wsoawt, bsoaw)
//   b in [20200,20456):    fused tail weights Wfcat = (Wo@Wagg)^T bf16, bf
// ---------------------------------------------------------------------------
__global__ __launch_bounds__(256) void prep_all(
    const float* __restrict__ q0, const float* __restrict__ q1,
    const float* __restrict__ f0, const float* __restrict__ f1,
    const float* __restrict__ Wv, const float* __restrict__ Wso,
    const float* __restrict__ Waw, const float* __restrict__ bso,
    const float* __restrict__ baw,
    const float* __restrict__ Wo, const float* __restrict__ Wagg,
    const float* __restrict__ bo, const float* __restrict__ bagg,
    unsigned short* __restrict__ Qb0, unsigned short* __restrict__ Qb1,
    unsigned short* __restrict__ Fb0, unsigned short* __restrict__ Fb1,
    unsigned short* __restrict__ Wvt, unsigned short* __restrict__ Wsoawt,
    float* __restrict__ bsoaw,
    unsigned short* __restrict__ Wfcat, float* __restrict__ bfused)
{
    const int b = blockIdx.x;
    if (b < 19560) {
        const int tsel = b / 4890;
        const int x = b - tsel * 4890;
        const float* s = (tsel & 2) ? ((tsel & 1) ? f1 : f0) : ((tsel & 1) ? q1 : q0);
        unsigned short* d = (tsel & 2) ? ((tsel & 1) ? Fb1 : Fb0) : ((tsel & 1) ? Qb1 : Qb0);
        size_t i = ((size_t)x * 256 + threadIdx.x) * 8;
        float4 a = *(const float4*)(s + i);
        float4 c = *(const float4*)(s + i + 4);
        union { uint4 u; unsigned short h[8]; } t;
        t.h[0] = f2bf(a.x); t.h[1] = f2bf(a.y); t.h[2] = f2bf(a.z); t.h[3] = f2bf(a.w);
        t.h[4] = f2bf(c.x); t.h[5] = f2bf(c.y); t.h[6] = f2bf(c.z); t.h[7] = f2bf(c.w);
        *(uint4*)(d + i) = t.u;
    } else if (b < 19560 + 640) {
        int o = (b - 19560) * 256 + threadIdx.x;
        if (o < 65536) {
            int n = o >> 8, k = o & 255;
            Wvt[o] = f2bf(Wv[(size_t)k * 256 + n]);
        } else {
            int p = o - 65536;
            int n = p >> 8, k = p & 255;
            float v = (n < 256) ? Wso[(size_t)k * 256 + n] : Waw[(size_t)k * 128 + (n - 256)];
            Wsoawt[p] = f2bf(v);
        }
        if (o < 384) bsoaw[o] = (o < 256) ? bso[o] : baw[o - 256];
    } else {
        int k = b - 20200;
        int n = threadIdx.x;
        float s0 = 0.f, s1 = 0.f;
        for (int j = 0; j < 256; j++) {
            float w = Wo[k * 256 + j];
            s0 += w * Wagg[j * 256 + n];
            s1 += w * Wagg[(256 + j) * 256 + n];
        }
        Wfcat[(size_t)n * 512 + k]       = f2bf(s0);
        Wfcat[(size_t)n * 512 + 256 + k] = f2bf(s1);
        if (k == 0) {
            float bb = bagg[n];
            for (int j = 0; j < 256; j++)
                bb += bo[j] * (Wagg[j * 256 + n] + Wagg[(256 + j) * 256 + n]);
            bfused[n] = bb;
        }
    }
}

// ---------------------------------------------------------------------------
// Batched bf16 MFMA GEMM: C_z = A_z @ Bt^T (+bias), z = blockIdx.z
// A: bf16 [M][lda]; Bt: bf16 [N][K]. 128x128 tile, BK=64, 4 waves, 4x4 MFMA.
// Staging: global_load_lds width=16 DMA, LDS linear [128][128B], XOR chunk
// swizzle (source-side pre-swizzle + swizzled ds_read).
// mode 0: store fp32 at C[row*ldc+col]
// mode 2: store bf16 head-major scatter (n, h, pos, d)  [value tensor]
// ---------------------------------------------------------------------------
__global__ __launch_bounds__(256) void gemm_multi(
    const unsigned short* __restrict__ A0, const unsigned short* __restrict__ A1,
    const unsigned short* __restrict__ Bt, const float* __restrict__ bias,
    void* __restrict__ C0, void* __restrict__ C1,
    int M, int K, int lda, int N, int ldc, int mode)
{
    __shared__ __align__(16) unsigned short As[128 * 64];
    __shared__ __align__(16) unsigned short Bs[128 * 64];

    const int z = blockIdx.z;
    const unsigned short* A = z ? A1 : A0;
    void* Cv = z ? C1 : C0;

    const int tid  = threadIdx.x;
    const int w    = tid >> 6, lane = tid & 63;
    const int wm = w >> 1, wn = w & 1;
    const int m0 = blockIdx.y * 128, n0 = blockIdx.x * 128;
    const int lr = lane & 15, quad = lane >> 4;

    const int sr  = lane >> 3;
    const int scl = (lane & 7) ^ sr;
    const int colb = scl * 8;
    size_t arow[4], brow[4];
    #pragma unroll
    for (int j = 0; j < 4; j++) {
        int r = (w * 4 + j) * 8 + sr;
        int ra = m0 + r; if (ra > M - 1) ra = M - 1;
        arow[j] = (size_t)ra * lda;
        brow[j] = (size_t)(n0 + r) * K;
    }

    const f32x4 zero = {0.f, 0.f, 0.f, 0.f};
    f32x4 acc[4][4];
    #pragma unroll
    for (int i = 0; i < 4; i++)
        #pragma unroll
        for (int j = 0; j < 4; j++) acc[i][j] = zero;

    for (int t = 0; t < K; t += 64) {
        #pragma unroll
        for (int j = 0; j < 4; j++) {
            int lofs = __builtin_amdgcn_readfirstlane((w * 4 + j) * 1024);
            __builtin_amdgcn_global_load_lds(
                (const __attribute__((address_space(1))) void*)(A + arow[j] + t + colb),
                (__attribute__((address_space(3))) void*)((char*)As + lofs), 16, 0, 0);
            __builtin_amdgcn_global_load_lds(
                (const __attribute__((address_space(1))) void*)(Bt + brow[j] + t + colb),
                (__attribute__((address_space(3))) void*)((char*)Bs + lofs), 16, 0, 0);
        }
        __syncthreads();

        #pragma unroll
        for (int kk = 0; kk < 2; kk++) {
            bf16x8 af[4], bff[4];
            #pragma unroll
            for (int mi = 0; mi < 4; mi++) {
                int R = wm * 64 + mi * 16 + lr;
                int pc = ((kk * 4 + quad) ^ (lr & 7)) * 16;
                af[mi] = *(const bf16x8*)((const char*)As + R * 128 + pc);
            }
            #pragma unroll
            for (int ni = 0; ni < 4; ni++) {
                int R = wn * 64 + ni * 16 + lr;
                int pc = ((kk * 4 + quad) ^ (lr & 7)) * 16;
                bff[ni] = *(const bf16x8*)((const char*)Bs + R * 128 + pc);
            }
            #pragma unroll
            for (int mi = 0; mi < 4; mi++)
                #pragma unroll
                for (int ni = 0; ni < 4; ni++)
                    acc[mi][ni] = __builtin_amdgcn_mfma_f32_16x16x32_bf16(
                        af[mi], bff[ni], acc[mi][ni], 0, 0, 0);
        }
        __syncthreads();
    }

    float* Cf = (float*)Cv;
    unsigned short* Cb = (unsigned short*)Cv;
    #pragma unroll
    for (int mi = 0; mi < 4; mi++) {
        #pragma unroll
        for (int reg = 0; reg < 4; reg++) {
            int row = m0 + wm * 64 + mi * 16 + quad * 4 + reg;
            if (row >= M) continue;
            #pragma unroll
            for (int ni = 0; ni < 4; ni++) {
                int col = n0 + wn * 64 + ni * 16 + lr;
                float v = acc[mi][ni][reg];
                if (bias) v += bias[col];
                if (mode == 0) {
                    Cf[(size_t)row * ldc + col] = v;
                } else {
                    int n = row >= LQ ? 1 : 0;
                    int pos = row - n * LQ;
                    int h = col >> 5, d = col & 31;
                    Cb[((size_t)(n * NHEADS + h) * LEN + pos) * HDIM + d] = f2bf(v);
                }
            }
        }
    }
}

// ---------------------------------------------------------------------------
// Logits GEMM for BOTH iters + fused joint softmax.
// One block = 128 rows x 128 logit cols, two K-passes (z=0,1) -> acc[2].
// Joint softmax over 32 = {16 cols of head h, both z}: the 16 cols of head
// h=(wn*4+ni) live across lanes lr=0..15 of a quad -> 4x shfl_xor reduce.
// Writes NORMALIZED attention weights to QS0/QS1 cols [256..384).
// ---------------------------------------------------------------------------
__global__ __launch_bounds__(256) void gemm_logits(
    const unsigned short* __restrict__ A0, const unsigned short* __restrict__ A1,
    const unsigned short* __restrict__ Bt,   // Wsoawt (384 x 256), rows 256..383
    const float* __restrict__ bias,          // bsoaw
    float* __restrict__ C0, float* __restrict__ C1, int M)
{
    __shared__ __align__(16) unsigned short As[128 * 64];
    __shared__ __align__(16) unsigned short Bs[128 * 64];

    const int tid  = threadIdx.x;
    const int w    = tid >> 6, lane = tid & 63;
    const int wm = w >> 1, wn = w & 1;
    const int m0 = blockIdx.x * 128;
    const int lr = lane & 15, quad = lane >> 4;

    const int sr  = lane >> 3;
    const int scl = (lane & 7) ^ sr;
    const int colb = scl * 8;
    size_t arow[4], brow[4];
    #pragma unroll
    for (int j = 0; j < 4; j++) {
        int r = (w * 4 + j) * 8 + sr;
        int ra = m0 + r; if (ra > M - 1) ra = M - 1;
        arow[j] = (size_t)ra * 256;
        brow[j] = (size_t)(256 + r) * 256;   // logit rows of Wsoawt
    }

    const f32x4 zero = {0.f, 0.f, 0.f, 0.f};
    f32x4 acc[2][4][4];
    #pragma unroll
    for (int zz = 0; zz < 2; zz++)
        #pragma unroll
        for (int i = 0; i < 4; i++)
            #pragma unroll
            for (int j = 0; j < 4; j++) acc[zz][i][j] = zero;

    #pragma unroll
    for (int z = 0; z < 2; z++) {
        const unsigned short* A = z ? A1 : A0;
        for (int t = 0; t < 256; t += 64) {
            #pragma unroll
            for (int j = 0; j < 4; j++) {
                int lofs = __builtin_amdgcn_readfirstlane((w * 4 + j) * 1024);
                __builtin_amdgcn_global_load_lds(
                    (const __attribute__((address_space(1))) void*)(A + arow[j] + t + colb),
                    (__attribute__((address_space(3))) void*)((char*)As + lofs), 16, 0, 0);
                __builtin_amdgcn_global_load_lds(
                    (const __attribute__((address_space(1))) void*)(Bt + brow[j] + t + colb),
                    (__attribute__((address_space(3))) void*)((char*)Bs + lofs), 16, 0, 0);
            }
            __syncthreads();
            #pragma unroll
            for (int kk = 0; kk < 2; kk++) {
                bf16x8 af[4], bff[4];
                #pragma unroll
                for (int mi = 0; mi < 4; mi++) {
                    int R = wm * 64 + mi * 16 + lr;
                    int pc = ((kk * 4 + quad) ^ (lr & 7)) * 16;
                    af[mi] = *(const bf16x8*)((const char*)As + R * 128 + pc);
                }
                #pragma unroll
                for (int ni = 0; ni < 4; ni++) {
                    int R = wn * 64 + ni * 16 + lr;
                    int pc = ((kk * 4 + quad) ^ (lr & 7)) * 16;
                    bff[ni] = *(const bf16x8*)((const char*)Bs + R * 128 + pc);
                }
                #pragma unroll
                for (int mi = 0; mi < 4; mi++)
                    #pragma unroll
                    for (int ni = 0; ni < 4; ni++)
                        acc[z][mi][ni] = __builtin_amdgcn_mfma_f32_16x16x32_bf16(
                            af[mi], bff[ni], acc[z][mi][ni], 0, 0, 0);
            }
            __syncthreads();
        }
    }

    // bias per owned column (b_aw; zeros in this model, kept general)
    float bv[4];
    #pragma unroll
    for (int ni = 0; ni < 4; ni++) bv[ni] = bias[256 + wn * 64 + ni * 16 + lr];

    // in-register joint softmax + store
    #pragma unroll
    for (int mi = 0; mi < 4; mi++) {
        #pragma unroll
        for (int reg = 0; reg < 4; reg++) {
            int row = m0 + wm * 64 + mi * 16 + quad * 4 + reg;
            #pragma unroll
            for (int ni = 0; ni < 4; ni++) {
                float a = acc[0][mi][ni][reg] + bv[ni];
                float c = acc[1][mi][ni][reg] + bv[ni];
                float m = fmaxf(a, c);
                #pragma unroll
                for (int d = 1; d < 16; d <<= 1) m = fmaxf(m, __shfl_xor(m, d));
                float ea = expf(a - m), ec = expf(c - m);
                float s = ea + ec;
                #pragma unroll
                for (int d = 1; d < 16; d <<= 1) s += __shfl_xor(s, d);
                float inv = 1.0f / s;
                if (row < M) {
                    int col = 256 + wn * 64 + ni * 16 + lr;
                    C0[(size_t)row * LDQS + col] = ea * inv;
                    C1[(size_t)row * LDQS + col] = ec * inv;
                }
            }
        }
    }
}

// ---------------------------------------------------------------------------
// Merged deformable sampling (both iters), v5: two-pass LDS staging.
//  Pass p stages 8 points (levels 2p, 2p+1): lane lj handles level
//  2p+(lj>>1), points (lj&1)*2 .. +1 -> each point computed exactly once.
//  LDS 12.2 KB (was 24.6) -> 8 blocks/CU (wave cap). Planes padded to 65
//  entries: quartet's simultaneous writes hit 4 distinct bank groups
//  (Swt group=(sp+ql)%8 with sp spread {i,i+2,i+4,i+6}; Sidx banks 2sp+2ql),
//  reads conflict-free / 2-way(free).
//  Gather layout unchanged: 4 lanes/query, lane owns 8 dims, dwordx4/corner.
// ---------------------------------------------------------------------------
#define QCHUNK 64
#define CHUNKS ((LQ + QCHUNK - 1) / QCHUNK)   // 306

__global__ __launch_bounds__(256) void ms_sample(
    const unsigned short* __restrict__ V0, const unsigned short* __restrict__ V1,
    const float* __restrict__ QS0, const float* __restrict__ QS1,
    const float* __restrict__ refp, unsigned short* __restrict__ Ocat)
{
    __shared__ unsigned short Sidx[8][65][4];  // [plane][ql][corner] u16 row idx
    __shared__ float          Swt [8][65][4];  // [plane][ql][corner] weight

    const int b = blockIdx.x;
    const int h = b & 7;
    const int rest = b >> 3;               // (it*2+n)*CHUNKS + chunk
    const int chunk = rest % CHUNKS;
    const int inn   = rest / CHUNKS;       // it*2 + n
    const int n  = inn & 1;
    const int it = inn >> 1;

    const int tid = threadIdx.x;
    const int ql  = tid >> 2;              // 0..63 query slot
    const int lj  = tid & 3;
    const int qraw = chunk * QCHUNK + ql;
    const bool valid = qraw < LQ;
    const int q  = valid ? qraw : LQ - 1;
    const int nq = n * LQ + q;

    const unsigned short* __restrict__ val = it ? V1 : V0;
    const float* __restrict__ QS = it ? QS1 : QS0;
    const unsigned short* __restrict__ vb2 =
        val + (size_t)(n * NHEADS + h) * LEN * HDIM;

    const int Hs[4] = {92, 46, 23, 12};
    const int Ws[4] = {160, 80, 40, 20};
    const int Ss[4] = {0, 14720, 18400, 19320};

    const float* prow = QS + (size_t)nq * LDQS;
    const int dl = lj << 3;                // phase-2 dim quarter
    const unsigned short* __restrict__ vdl = vb2 + dl;

    f32x2 acc[4];
    #pragma unroll
    for (int i = 0; i < 4; i++) acc[i] = (f32x2){0.f, 0.f};

    auto corner = [&](unsigned int eo, float wgt) {
        const uint4 c = *(const uint4*)(vdl + eo);
        const f32x2 w2 = {wgt, wgt};
        acc[0] += w2 * bfpair(c.x);
        acc[1] += w2 * bfpair(c.y);
        acc[2] += w2 * bfpair(c.z);
        acc[3] += w2 * bfpair(c.w);
    };

    #pragma unroll
    for (int pass = 0; pass < 2; pass++) {
        // ---- phase 1: stage levels 2*pass, 2*pass+1 (2 points/lane) ----
        {
            const int lvl = lj >> 1;                 // 0,1 within pass
            const int l   = (pass << 1) | lvl;       // global level
            const int kb  = (lj & 1) << 1;           // 0 or 2
            const int H = Hs[l], W = Ws[l], S = Ss[l];
            const float2 rp = *(const float2*)(refp + (size_t)nq * 8 + l * 2);
            const float fx = rp.x * (float)W - 0.5f;
            const float fy = rp.y * (float)H - 0.5f;
            const float4 off = *(const float4*)(prow + (h << 5) + l * 8 + (kb << 1));
            const float2 aw2 = *(const float2*)(prow + 256 + (h << 4) + (l << 2) + kb);
            const float oxs[2] = {off.x, off.z};
            const float oys[2] = {off.y, off.w};
            const float avs[2] = {aw2.x, aw2.y};
            #pragma unroll
            for (int i = 0; i < 2; i++) {
                const float x = fx + oxs[i];
                const float y = fy + oys[i];
                const float x0f = floorf(x), y0f = floorf(y);
                const int x0 = (int)x0f, y0 = (int)y0f;
                const float wx1 = x - x0f, wy1 = y - y0f;
                const float wx0 = 1.0f - wx1, wy0 = 1.0f - wy1;
                const int xc0 = min(max(x0, 0), W - 1);
                const int xc1 = min(max(x0 + 1, 0), W - 1);
                const int yc0 = min(max(y0, 0), H - 1);
                const int yc1 = min(max(y0 + 1, 0), H - 1);
                const float a = avs[i];
                const float ay0 = ((unsigned int)y0 < (unsigned int)H) ? a * wy0 : 0.f;
                const float ay1 = ((unsigned int)(y0 + 1) < (unsigned int)H) ? a * wy1 : 0.f;
                const float mx0 = ((unsigned int)x0 < (unsigned int)W) ? wx0 : 0.f;
                const float mx1 = ((unsigned int)(x0 + 1) < (unsigned int)W) ? wx1 : 0.f;
                const int r0 = S + yc0 * W, r1 = S + yc1 * W;
                union { uint2 u; unsigned short s4[4]; } ip;
                ip.s4[0] = (unsigned short)(r0 + xc0);
                ip.s4[1] = (unsigned short)(r0 + xc1);
                ip.s4[2] = (unsigned short)(r1 + xc0);
                ip.s4[3] = (unsigned short)(r1 + xc1);
                const int sp = (lvl << 2) + kb + i;  // 0..7, all distinct per step
                *(uint2*)&Sidx[sp][ql][0] = ip.u;
                float4 w4 = make_float4(ay0 * mx0, ay0 * mx1, ay1 * mx0, ay1 * mx1);
                *(float4*)&Swt[sp][ql][0] = w4;
            }
        }
        __syncthreads();

        // ---- phase 2: gather 8 staged points ----
        #pragma unroll
        for (int p = 0; p < 8; p++) {
            const uint2 i2 = *(const uint2*)&Sidx[p][ql][0];
            const float4 w4 = *(const float4*)&Swt[p][ql][0];
            corner((i2.x & 0xFFFFu) << 5, w4.x);
            corner((i2.x >> 16) << 5, w4.y);
            corner((i2.y & 0xFFFFu) << 5, w4.z);
            corner((i2.y >> 16) << 5, w4.w);
        }
        if (pass == 0) __syncthreads();
    }

    if (valid) {
        union { uint4 u; unsigned short s[8]; } t;
        #pragma unroll
        for (int i = 0; i < 4; i++) {
            t.s[2 * i]     = f2bf(acc[i].x);
            t.s[2 * i + 1] = f2bf(acc[i].y);
        }
        *(uint4*)&Ocat[(size_t)nq * 512 + it * 256 + h * HDIM + dl] = t.u;
    }
}

// ---------------------------------------------------------------------------
extern "C" void kernel_launch(void* const* d_in, const int* in_sizes, int n_in,
                              void* d_out, int out_size, void* d_ws, size_t ws_size,
                              hipStream_t stream)
{
    const float* q0    = (const float*)d_in[0];
    const float* q1    = (const float*)d_in[1];
    const float* refp  = (const float*)d_in[2];
    const float* f0    = (const float*)d_in[3];
    const float* f1    = (const float*)d_in[4];
    const float* W_so  = (const float*)d_in[7];
    const float* b_so  = (const float*)d_in[8];
    const float* W_aw  = (const float*)d_in[9];
    const float* b_aw  = (const float*)d_in[10];
    const float* W_v   = (const float*)d_in[11];
    const float* b_v   = (const float*)d_in[12];
    const float* W_o   = (const float*)d_in[13];
    const float* b_o   = (const float*)d_in[14];
    const float* W_agg = (const float*)d_in[15];
    const float* b_agg = (const float*)d_in[16];
    float* out = (float*)d_out;

    float* ws = (float*)d_ws;
    float* QS0 = ws;                                        // NQ*384 fp32
    float* QS1 = QS0 + (size_t)NQ * LDQS;                   // NQ*384 fp32
    unsigned short* V0   = (unsigned short*)(QS1 + (size_t)NQ * LDQS);  // NQ*256 bf16
    unsigned short* V1   = V0 + (size_t)NQ * 256;
    unsigned short* Ocat = V1 + (size_t)NQ * 256;           // NQ*512 bf16
    unsigned short* Wvt    = Ocat + (size_t)NQ * 512;       // 65536
    unsigned short* Wsoawt = Wvt + 65536;                   // 98304
    unsigned short* Wfcat  = Wsoawt + 98304;                // 131072
    float* bsoaw = (float*)(Wfcat + 131072);                // 384
    float* bfus  = bsoaw + 384;                             // 256

    // bf16 A copies, zero extra workspace (lifetime-audited aliases):
    //  Qb0/Qb1 alias V0/V1   (q-side GEMMs read them BEFORE value-GEMM writes V)
    //  Fb0/Fb1 alias Ocat    (value-GEMM reads them BEFORE ms_sample writes Ocat)
    unsigned short* Qb0 = V0;
    unsigned short* Qb1 = V1;
    unsigned short* Fb0 = Ocat;
    unsigned short* Fb1 = Ocat + (size_t)NQ * 256;

    const int MB = (NQ + 127) / 128;   // 306
    dim3 blk(256);

    // merged preprocessing: converts + weight prep + fused tail weights
    prep_all<<<20456, blk, 0, stream>>>(
        q0, q1, f0, f1, W_v, W_so, W_aw, b_so, b_aw, W_o, W_agg, b_o, b_agg,
        Qb0, Qb1, Fb0, Fb1, Wvt, Wsoawt, bsoaw, Wfcat, bfus);

    // q-side offsets (cols 0..255) for both iters
    gemm_multi<<<dim3(2, MB, 2), blk, 0, stream>>>(
        Qb0, Qb1, Wsoawt, bsoaw, QS0, QS1, NQ, 256, 256, 384, LDQS, 0);

    // logits for both iters + fused joint softmax -> QS cols 256..383
    gemm_logits<<<MB, blk, 0, stream>>>(
        Qb0, Qb1, Wsoawt, bsoaw, QS0, QS1, NQ);

    // values for both iters, head-major scatter
    gemm_multi<<<dim3(2, MB, 2), blk, 0, stream>>>(
        Fb0, Fb1, Wvt, b_v, V0, V1, NQ, 256, 256, 256, 256, 2);

    // merged sampler (both iters) -> Ocat (overwrites Fb after value-GEMM)
    ms_sample<<<2 * 2 * CHUNKS * 8, blk, 0, stream>>>(V0, V1, QS0, QS1, refp, Ocat);

    // single K=512 tail GEMM -> out
    gemm_multi<<<dim3(2, MB, 1), blk, 0, stream>>>(
        Ocat, Ocat, Wfcat, bfus, out, out, NQ, 512, 512, 256, 256, 0);
}

// Round 8
// 479.984 us; speedup vs baseline: 1.1770x; 1.1770x over previous
//
#include <hip/hip_runtime.h>
#include <math.h>

#define NBATCH 2
#define LQ     19560
#define LEN    19560
#define NQ     (NBATCH * LQ)      // 39120
#define DMODEL 256
#define NHEADS 8
#define HDIM   32
#define NLEV   4
#define NPTS   4
#define LDQS   384                // QS row stride fp32: [0..255]=offsets, [256..383]=aw
                                  // aw bytes [1024,1536) double as bf16 Qb before logits

typedef __bf16 bf16x8 __attribute__((ext_vector_type(8)));
typedef float  f32x4  __attribute__((ext_vector_type(4)));
typedef float  f32x2  __attribute__((ext_vector_type(2)));

__device__ inline unsigned short f2bf(float f) {
    unsigned int u = __float_as_uint(f);
    u += 0x7FFFu + ((u >> 16) & 1u);     // RNE
    return (unsigned short)(u >> 16);
}
// two bf16 packed in a dword -> two exact f32 (lo = u<<16, hi = u & 0xFFFF0000)
__device__ inline f32x2 bfpair(unsigned int u) {
    f32x2 r;
    r.x = __uint_as_float(u << 16);
    r.y = __uint_as_float(u & 0xFFFF0000u);
    return r;
}

// ---------------------------------------------------------------------------
// Merged preprocessing (one dispatch, disjoint outputs):
//   b in [0,19560):     fp32->bf16 convert. q0/q1 -> Qb embedded in QS aw bytes
//                       (row*768 + 512 shorts); f0/f1 -> Fb (linear, = Ocat).
//   b in [19560,20200): weight transpose/pack (Wvt, Wsoawt, bsoaw)
//   b in [20200,20456): fused tail weights Wfcat = (Wo@Wagg)^T bf16, bfused
// ---------------------------------------------------------------------------
__global__ __launch_bounds__(256) void prep_all(
    const float* __restrict__ q0, const float* __restrict__ q1,
    const float* __restrict__ f0, const float* __restrict__ f1,
    const float* __restrict__ Wv, const float* __restrict__ Wso,
    const float* __restrict__ Waw, const float* __restrict__ bso,
    const float* __restrict__ baw,
    const float* __restrict__ Wo, const float* __restrict__ Wagg,
    const float* __restrict__ bo, const float* __restrict__ bagg,
    unsigned short* __restrict__ Qb0, unsigned short* __restrict__ Qb1,
    unsigned short* __restrict__ Fb0, unsigned short* __restrict__ Fb1,
    unsigned short* __restrict__ Wvt, unsigned short* __restrict__ Wsoawt,
    float* __restrict__ bsoaw,
    unsigned short* __restrict__ Wfcat, float* __restrict__ bfused)
{
    const int b = blockIdx.x;
    if (b < 19560) {
        const int tsel = b / 4890;
        const int x = b - tsel * 4890;
        const float* s = (tsel & 2) ? ((tsel & 1) ? f1 : f0) : ((tsel & 1) ? q1 : q0);
        unsigned short* d = (tsel & 2) ? ((tsel & 1) ? Fb1 : Fb0) : ((tsel & 1) ? Qb1 : Qb0);
        size_t i = ((size_t)x * 256 + threadIdx.x) * 8;
        float4 a = *(const float4*)(s + i);
        float4 c = *(const float4*)(s + i + 4);
        union { uint4 u; unsigned short h[8]; } t;
        t.h[0] = f2bf(a.x); t.h[1] = f2bf(a.y); t.h[2] = f2bf(a.z); t.h[3] = f2bf(a.w);
        t.h[4] = f2bf(c.x); t.h[5] = f2bf(c.y); t.h[6] = f2bf(c.z); t.h[7] = f2bf(c.w);
        if (tsel & 2) {
            *(uint4*)(d + i) = t.u;                         // Fb linear
        } else {
            size_t row = i >> 8; int c8 = (int)(i & 255);   // Qb strided into QS rows
            *(uint4*)(d + row * 768 + 512 + c8) = t.u;
        }
    } else if (b < 19560 + 640) {
        int o = (b - 19560) * 256 + threadIdx.x;
        if (o < 65536) {
            int n = o >> 8, k = o & 255;
            Wvt[o] = f2bf(Wv[(size_t)k * 256 + n]);
        } else {
            int p = o - 65536;
            int n = p >> 8, k = p & 255;
            float v = (n < 256) ? Wso[(size_t)k * 256 + n] : Waw[(size_t)k * 128 + (n - 256)];
            Wsoawt[p] = f2bf(v);
        }
        if (o < 384) bsoaw[o] = (o < 256) ? bso[o] : baw[o - 256];
    } else {
        int k = b - 20200;
        int n = threadIdx.x;
        float s0 = 0.f, s1 = 0.f;
        for (int j = 0; j < 256; j++) {
            float w = Wo[k * 256 + j];
            s0 += w * Wagg[j * 256 + n];
            s1 += w * Wagg[(256 + j) * 256 + n];
        }
        Wfcat[(size_t)n * 512 + k]       = f2bf(s0);
        Wfcat[(size_t)n * 512 + 256 + k] = f2bf(s1);
        if (k == 0) {
            float bb = bagg[n];
            for (int j = 0; j < 256; j++)
                bb += bo[j] * (Wagg[j * 256 + n] + Wagg[(256 + j) * 256 + n]);
            bfused[n] = bb;
        }
    }
}

// ---------------------------------------------------------------------------
// Merged mid GEMMs (one dispatch): grid (2, MB, 4).
//  z in {0,1}: offsets GEMM   C=QS_z cols 0..255 fp32, A=Qb_z (lda=768,
//              embedded in QS aw bytes), Bt=Wsoawt rows 0..255, bias=bsoaw.
//  z in {2,3}: value GEMM     C=V_{z-2} bf16 head-major scatter, A=Fb_{z-2}
//              (lda=256), Bt=Wvt, bias=b_v.
//  K=256, 128x128 tile, BK=64, global_load_lds w16, XOR chunk swizzle.
//  Merging the two independent GEMMs fills each other's ramp/tail.
// ---------------------------------------------------------------------------
__global__ __launch_bounds__(256) void gemm_mid(
    const unsigned short* __restrict__ Qa0, const unsigned short* __restrict__ Qa1,
    const unsigned short* __restrict__ Fb0, const unsigned short* __restrict__ Fb1,
    const unsigned short* __restrict__ Wsoawt, const unsigned short* __restrict__ Wvt,
    const float* __restrict__ bsoaw, const float* __restrict__ bv,
    float* __restrict__ QS0, float* __restrict__ QS1,
    unsigned short* __restrict__ V0, unsigned short* __restrict__ V1)
{
    __shared__ __align__(16) unsigned short As[128 * 64];
    __shared__ __align__(16) unsigned short Bs[128 * 64];

    const int z = blockIdx.z;
    const int isOff = (z < 2);
    const int zz = z & 1;
    const unsigned short* A = isOff ? (zz ? Qa1 : Qa0) : (zz ? Fb1 : Fb0);
    const unsigned short* Bt = isOff ? Wsoawt : Wvt;
    const float* bias = isOff ? bsoaw : bv;
    const int lda = isOff ? 768 : 256;

    const int tid  = threadIdx.x;
    const int w    = tid >> 6, lane = tid & 63;
    const int wm = w >> 1, wn = w & 1;
    const int m0 = blockIdx.y * 128, n0 = blockIdx.x * 128;
    const int lr = lane & 15, quad = lane >> 4;

    const int sr  = lane >> 3;
    const int scl = (lane & 7) ^ sr;
    const int colb = scl * 8;
    size_t arow[4], brow[4];
    #pragma unroll
    for (int j = 0; j < 4; j++) {
        int r = (w * 4 + j) * 8 + sr;
        int ra = m0 + r; if (ra > NQ - 1) ra = NQ - 1;
        arow[j] = (size_t)ra * lda;
        brow[j] = (size_t)(n0 + r) * 256;
    }

    const f32x4 zero = {0.f, 0.f, 0.f, 0.f};
    f32x4 acc[4][4];
    #pragma unroll
    for (int i = 0; i < 4; i++)
        #pragma unroll
        for (int j = 0; j < 4; j++) acc[i][j] = zero;

    for (int t = 0; t < 256; t += 64) {
        #pragma unroll
        for (int j = 0; j < 4; j++) {
            int lofs = __builtin_amdgcn_readfirstlane((w * 4 + j) * 1024);
            __builtin_amdgcn_global_load_lds(
                (const __attribute__((address_space(1))) void*)(A + arow[j] + t + colb),
                (__attribute__((address_space(3))) void*)((char*)As + lofs), 16, 0, 0);
            __builtin_amdgcn_global_load_lds(
                (const __attribute__((address_space(1))) void*)(Bt + brow[j] + t + colb),
                (__attribute__((address_space(3))) void*)((char*)Bs + lofs), 16, 0, 0);
        }
        __syncthreads();

        #pragma unroll
        for (int kk = 0; kk < 2; kk++) {
            bf16x8 af[4], bff[4];
            #pragma unroll
            for (int mi = 0; mi < 4; mi++) {
                int R = wm * 64 + mi * 16 + lr;
                int pc = ((kk * 4 + quad) ^ (lr & 7)) * 16;
                af[mi] = *(const bf16x8*)((const char*)As + R * 128 + pc);
            }
            #pragma unroll
            for (int ni = 0; ni < 4; ni++) {
                int R = wn * 64 + ni * 16 + lr;
                int pc = ((kk * 4 + quad) ^ (lr & 7)) * 16;
                bff[ni] = *(const bf16x8*)((const char*)Bs + R * 128 + pc);
            }
            #pragma unroll
            for (int mi = 0; mi < 4; mi++)
                #pragma unroll
                for (int ni = 0; ni < 4; ni++)
                    acc[mi][ni] = __builtin_amdgcn_mfma_f32_16x16x32_bf16(
                        af[mi], bff[ni], acc[mi][ni], 0, 0, 0);
        }
        __syncthreads();
    }

    float* Cf = isOff ? (zz ? QS1 : QS0) : nullptr;
    unsigned short* Cb = isOff ? nullptr : (zz ? V1 : V0);
    #pragma unroll
    for (int mi = 0; mi < 4; mi++) {
        #pragma unroll
        for (int reg = 0; reg < 4; reg++) {
            int row = m0 + wm * 64 + mi * 16 + quad * 4 + reg;
            if (row >= NQ) continue;
            #pragma unroll
            for (int ni = 0; ni < 4; ni++) {
                int col = n0 + wn * 64 + ni * 16 + lr;
                float v = acc[mi][ni][reg] + bias[col];
                if (isOff) {
                    Cf[(size_t)row * LDQS + col] = v;
                } else {
                    int n = row >= LQ ? 1 : 0;
                    int pos = row - n * LQ;
                    int h = col >> 5, d = col & 31;
                    Cb[((size_t)(n * NHEADS + h) * LEN + pos) * HDIM + d] = f2bf(v);
                }
            }
        }
    }
}

// ---------------------------------------------------------------------------
// Logits GEMM for BOTH iters + fused joint softmax.
// A = Qb embedded in QS aw bytes (lda=768). Writes normalized attention
// weights back over those same aw bytes (fp32 cols 256..383) — panel-local:
// each block reads A only from its own 128-row panel and writes only its own
// panel's aw cols AFTER all its reads (epilogue).  MUST run after gemm_mid
// (which reads Qb) — stream order enforces this.
// ---------------------------------------------------------------------------
__global__ __launch_bounds__(256) void gemm_logits(
    const unsigned short* __restrict__ Qa0, const unsigned short* __restrict__ Qa1,
    const unsigned short* __restrict__ Bt,   // Wsoawt (384 x 256), rows 256..383
    const float* __restrict__ bias,          // bsoaw
    float* __restrict__ C0, float* __restrict__ C1)
{
    __shared__ __align__(16) unsigned short As[128 * 64];
    __shared__ __align__(16) unsigned short Bs[128 * 64];

    const int tid  = threadIdx.x;
    const int w    = tid >> 6, lane = tid & 63;
    const int wm = w >> 1, wn = w & 1;
    const int m0 = blockIdx.x * 128;
    const int lr = lane & 15, quad = lane >> 4;

    const int sr  = lane >> 3;
    const int scl = (lane & 7) ^ sr;
    const int colb = scl * 8;
    size_t arow[4], brow[4];
    #pragma unroll
    for (int j = 0; j < 4; j++) {
        int r = (w * 4 + j) * 8 + sr;
        int ra = m0 + r; if (ra > NQ - 1) ra = NQ - 1;
        arow[j] = (size_t)ra * 768;
        brow[j] = (size_t)(256 + r) * 256;   // logit rows of Wsoawt
    }

    const f32x4 zero = {0.f, 0.f, 0.f, 0.f};
    f32x4 acc[2][4][4];
    #pragma unroll
    for (int zz = 0; zz < 2; zz++)
        #pragma unroll
        for (int i = 0; i < 4; i++)
            #pragma unroll
            for (int j = 0; j < 4; j++) acc[zz][i][j] = zero;

    #pragma unroll
    for (int z = 0; z < 2; z++) {
        const unsigned short* A = z ? Qa1 : Qa0;
        for (int t = 0; t < 256; t += 64) {
            #pragma unroll
            for (int j = 0; j < 4; j++) {
                int lofs = __builtin_amdgcn_readfirstlane((w * 4 + j) * 1024);
                __builtin_amdgcn_global_load_lds(
                    (const __attribute__((address_space(1))) void*)(A + arow[j] + t + colb),
                    (__attribute__((address_space(3))) void*)((char*)As + lofs), 16, 0, 0);
                __builtin_amdgcn_global_load_lds(
                    (const __attribute__((address_space(1))) void*)(Bt + brow[j] + t + colb),
                    (__attribute__((address_space(3))) void*)((char*)Bs + lofs), 16, 0, 0);
            }
            __syncthreads();
            #pragma unroll
            for (int kk = 0; kk < 2; kk++) {
                bf16x8 af[4], bff[4];
                #pragma unroll
                for (int mi = 0; mi < 4; mi++) {
                    int R = wm * 64 + mi * 16 + lr;
                    int pc = ((kk * 4 + quad) ^ (lr & 7)) * 16;
                    af[mi] = *(const bf16x8*)((const char*)As + R * 128 + pc);
                }
                #pragma unroll
                for (int ni = 0; ni < 4; ni++) {
                    int R = wn * 64 + ni * 16 + lr;
                    int pc = ((kk * 4 + quad) ^ (lr & 7)) * 16;
                    bff[ni] = *(const bf16x8*)((const char*)Bs + R * 128 + pc);
                }
                #pragma unroll
                for (int mi = 0; mi < 4; mi++)
                    #pragma unroll
                    for (int ni = 0; ni < 4; ni++)
                        acc[z][mi][ni] = __builtin_amdgcn_mfma_f32_16x16x32_bf16(
                            af[mi], bff[ni], acc[z][mi][ni], 0, 0, 0);
            }
            __syncthreads();
        }
    }

    float bv[4];
    #pragma unroll
    for (int ni = 0; ni < 4; ni++) bv[ni] = bias[256 + wn * 64 + ni * 16 + lr];

    // in-register joint softmax + store
    #pragma unroll
    for (int mi = 0; mi < 4; mi++) {
        #pragma unroll
        for (int reg = 0; reg < 4; reg++) {
            int row = m0 + wm * 64 + mi * 16 + quad * 4 + reg;
            #pragma unroll
            for (int ni = 0; ni < 4; ni++) {
                float a = acc[0][mi][ni][reg] + bv[ni];
                float c = acc[1][mi][ni][reg] + bv[ni];
                float m = fmaxf(a, c);
                #pragma unroll
                for (int d = 1; d < 16; d <<= 1) m = fmaxf(m, __shfl_xor(m, d));
                float ea = expf(a - m), ec = expf(c - m);
                float s = ea + ec;
                #pragma unroll
                for (int d = 1; d < 16; d <<= 1) s += __shfl_xor(s, d);
                float inv = 1.0f / s;
                if (row < NQ) {
                    int col = 256 + wn * 64 + ni * 16 + lr;
                    C0[(size_t)row * LDQS + col] = ea * inv;
                    C1[(size_t)row * LDQS + col] = ec * inv;
                }
            }
        }
    }
}

// ---------------------------------------------------------------------------
// Merged deformable sampling (both iters), v6 = v4 single-pass structure
// (which measured 128.8us) + 65-entry plane padding (kills the 5.64M
// bank-conflict cycles; the v5 two-pass split is reverted — it cost more in
// barrier serialization + halved gather ILP than conflicts saved).
//  Phase 1: lane lj owns level lj: computes 4 points, stages idx(u16)+wt(f32)
//           in planes lj*4+k.  Padded [16][65][4]: quartet writes hit
//           distinct bank groups; reads conflict-free / 2-way (free).
//  Phase 2: 16-point gather, 4 lanes/query, lane owns 8 dims, dwordx4/corner.
// ---------------------------------------------------------------------------
#define QCHUNK 64
#define CHUNKS ((LQ + QCHUNK - 1) / QCHUNK)   // 306

__global__ __launch_bounds__(256) void ms_sample(
    const unsigned short* __restrict__ V0, const unsigned short* __restrict__ V1,
    const float* __restrict__ QS0, const float* __restrict__ QS1,
    const float* __restrict__ refp, unsigned short* __restrict__ Ocat)
{
    __shared__ unsigned short Sidx[16][65][4];  // [plane][ql][corner] u16 row idx
    __shared__ float          Swt [16][65][4];  // [plane][ql][corner] weight

    const int b = blockIdx.x;
    const int h = b & 7;
    const int rest = b >> 3;               // (it*2+n)*CHUNKS + chunk
    const int chunk = rest % CHUNKS;
    const int inn   = rest / CHUNKS;       // it*2 + n
    const int n  = inn & 1;
    const int it = inn >> 1;

    const int tid = threadIdx.x;
    const int ql  = tid >> 2;              // 0..63 query slot
    const int lj  = tid & 3;
    const int qraw = chunk * QCHUNK + ql;
    const bool valid = qraw < LQ;
    const int q  = valid ? qraw : LQ - 1;
    const int nq = n * LQ + q;

    const unsigned short* __restrict__ val = it ? V1 : V0;
    const float* __restrict__ QS = it ? QS1 : QS0;
    const unsigned short* __restrict__ vb2 =
        val + (size_t)(n * NHEADS + h) * LEN * HDIM;

    const int Hs[4] = {92, 46, 23, 12};
    const int Ws[4] = {160, 80, 40, 20};
    const int Ss[4] = {0, 14720, 18400, 19320};

    const float* prow = QS + (size_t)nq * LDQS;

    // ---- phase 1: this lane's level only (4 points) ----
    {
        const int H = Hs[lj], W = Ws[lj], S = Ss[lj];
        const float4 o0 = *(const float4*)(prow + (h << 5) + lj * 8);
        const float4 o1 = *(const float4*)(prow + (h << 5) + lj * 8 + 4);
        const float4 a4 = *(const float4*)(prow + 256 + (h << 4) + lj * 4);
        const float2 rp = *(const float2*)(refp + (size_t)nq * 8 + lj * 2);
        const float fx = rp.x * (float)W - 0.5f;
        const float fy = rp.y * (float)H - 0.5f;
        const float oxs[4] = {o0.x, o0.z, o1.x, o1.z};
        const float oys[4] = {o0.y, o0.w, o1.y, o1.w};
        const float avs[4] = {a4.x, a4.y, a4.z, a4.w};
        #pragma unroll
        for (int k = 0; k < NPTS; k++) {
            const float x = fx + oxs[k];
            const float y = fy + oys[k];
            const float x0f = floorf(x), y0f = floorf(y);
            const int x0 = (int)x0f, y0 = (int)y0f;
            const float wx1 = x - x0f, wy1 = y - y0f;
            const float wx0 = 1.0f - wx1, wy0 = 1.0f - wy1;
            const int xc0 = min(max(x0, 0), W - 1);
            const int xc1 = min(max(x0 + 1, 0), W - 1);
            const int yc0 = min(max(y0, 0), H - 1);
            const int yc1 = min(max(y0 + 1, 0), H - 1);
            const float a = avs[k];
            const float ay0 = ((unsigned int)y0 < (unsigned int)H) ? a * wy0 : 0.f;
            const float ay1 = ((unsigned int)(y0 + 1) < (unsigned int)H) ? a * wy1 : 0.f;
            const float mx0 = ((unsigned int)x0 < (unsigned int)W) ? wx0 : 0.f;
            const float mx1 = ((unsigned int)(x0 + 1) < (unsigned int)W) ? wx1 : 0.f;
            const int r0 = S + yc0 * W, r1 = S + yc1 * W;
            union { uint2 u; unsigned short s4[4]; } ip;
            ip.s4[0] = (unsigned short)(r0 + xc0);
            ip.s4[1] = (unsigned short)(r0 + xc1);
            ip.s4[2] = (unsigned short)(r1 + xc0);
            ip.s4[3] = (unsigned short)(r1 + xc1);
            *(uint2*)&Sidx[lj * 4 + k][ql][0] = ip.u;
            float4 w4 = make_float4(ay0 * mx0, ay0 * mx1, ay1 * mx0, ay1 * mx1);
            *(float4*)&Swt[lj * 4 + k][ql][0] = w4;
        }
    }
    __syncthreads();

    // ---- phase 2: gather all 16 staged points ----
    const int dl = lj << 3;                // dim quarter 0,8,16,24
    const unsigned short* __restrict__ vdl = vb2 + dl;

    f32x2 acc[4];
    #pragma unroll
    for (int i = 0; i < 4; i++) acc[i] = (f32x2){0.f, 0.f};

    auto corner = [&](unsigned int eo, float wgt) {
        const uint4 c = *(const uint4*)(vdl + eo);
        const f32x2 w2 = {wgt, wgt};
        acc[0] += w2 * bfpair(c.x);
        acc[1] += w2 * bfpair(c.y);
        acc[2] += w2 * bfpair(c.z);
        acc[3] += w2 * bfpair(c.w);
    };

    #pragma unroll
    for (int p = 0; p < 16; p++) {
        const uint2 i2 = *(const uint2*)&Sidx[p][ql][0];
        const float4 w4 = *(const float4*)&Swt[p][ql][0];
        corner((i2.x & 0xFFFFu) << 5, w4.x);
        corner((i2.x >> 16) << 5, w4.y);
        corner((i2.y & 0xFFFFu) << 5, w4.z);
        corner((i2.y >> 16) << 5, w4.w);
    }

    if (valid) {
        union { uint4 u; unsigned short s[8]; } t;
        #pragma unroll
        for (int i = 0; i < 4; i++) {
            t.s[2 * i]     = f2bf(acc[i].x);
            t.s[2 * i + 1] = f2bf(acc[i].y);
        }
        *(uint4*)&Ocat[(size_t)nq * 512 + it * 256 + h * HDIM + dl] = t.u;
    }
}

// ---------------------------------------------------------------------------
// Tail GEMM (generic): C = A @ Bt^T + bias, fp32 out.
// ---------------------------------------------------------------------------
__global__ __launch_bounds__(256) void gemm_tail(
    const unsigned short* __restrict__ A, const unsigned short* __restrict__ Bt,
    const float* __restrict__ bias, float* __restrict__ C)
{
    __shared__ __align__(16) unsigned short As[128 * 64];
    __shared__ __align__(16) unsigned short Bs[128 * 64];

    const int tid  = threadIdx.x;
    const int w    = tid >> 6, lane = tid & 63;
    const int wm = w >> 1, wn = w & 1;
    const int m0 = blockIdx.y * 128, n0 = blockIdx.x * 128;
    const int lr = lane & 15, quad = lane >> 4;

    const int sr  = lane >> 3;
    const int scl = (lane & 7) ^ sr;
    const int colb = scl * 8;
    size_t arow[4], brow[4];
    #pragma unroll
    for (int j = 0; j < 4; j++) {
        int r = (w * 4 + j) * 8 + sr;
        int ra = m0 + r; if (ra > NQ - 1) ra = NQ - 1;
        arow[j] = (size_t)ra * 512;
        brow[j] = (size_t)(n0 + r) * 512;
    }

    const f32x4 zero = {0.f, 0.f, 0.f, 0.f};
    f32x4 acc[4][4];
    #pragma unroll
    for (int i = 0; i < 4; i++)
        #pragma unroll
        for (int j = 0; j < 4; j++) acc[i][j] = zero;

    for (int t = 0; t < 512; t += 64) {
        #pragma unroll
        for (int j = 0; j < 4; j++) {
            int lofs = __builtin_amdgcn_readfirstlane((w * 4 + j) * 1024);
            __builtin_amdgcn_global_load_lds(
                (const __attribute__((address_space(1))) void*)(A + arow[j] + t + colb),
                (__attribute__((address_space(3))) void*)((char*)As + lofs), 16, 0, 0);
            __builtin_amdgcn_global_load_lds(
                (const __attribute__((address_space(1))) void*)(Bt + brow[j] + t + colb),
                (__attribute__((address_space(3))) void*)((char*)Bs + lofs), 16, 0, 0);
        }
        __syncthreads();

        #pragma unroll
        for (int kk = 0; kk < 2; kk++) {
            bf16x8 af[4], bff[4];
            #pragma unroll
            for (int mi = 0; mi < 4; mi++) {
                int R = wm * 64 + mi * 16 + lr;
                int pc = ((kk * 4 + quad) ^ (lr & 7)) * 16;
                af[mi] = *(const bf16x8*)((const char*)As + R * 128 + pc);
            }
            #pragma unroll
            for (int ni = 0; ni < 4; ni++) {
                int R = wn * 64 + ni * 16 + lr;
                int pc = ((kk * 4 + quad) ^ (lr & 7)) * 16;
                bff[ni] = *(const bf16x8*)((const char*)Bs + R * 128 + pc);
            }
            #pragma unroll
            for (int mi = 0; mi < 4; mi++)
                #pragma unroll
                for (int ni = 0; ni < 4; ni++)
                    acc[mi][ni] = __builtin_amdgcn_mfma_f32_16x16x32_bf16(
                        af[mi], bff[ni], acc[mi][ni], 0, 0, 0);
        }
        __syncthreads();
    }

    #pragma unroll
    for (int mi = 0; mi < 4; mi++) {
        #pragma unroll
        for (int reg = 0; reg < 4; reg++) {
            int row = m0 + wm * 64 + mi * 16 + quad * 4 + reg;
            if (row >= NQ) continue;
            #pragma unroll
            for (int ni = 0; ni < 4; ni++) {
                int col = n0 + wn * 64 + ni * 16 + lr;
                C[(size_t)row * 256 + col] = acc[mi][ni][reg] + bias[col];
            }
        }
    }
}

// ---------------------------------------------------------------------------
extern "C" void kernel_launch(void* const* d_in, const int* in_sizes, int n_in,
                              void* d_out, int out_size, void* d_ws, size_t ws_size,
                              hipStream_t stream)
{
    const float* q0    = (const float*)d_in[0];
    const float* q1    = (const float*)d_in[1];
    const float* refp  = (const float*)d_in[2];
    const float* f0    = (const float*)d_in[3];
    const float* f1    = (const float*)d_in[4];
    const float* W_so  = (const float*)d_in[7];
    const float* b_so  = (const float*)d_in[8];
    const float* W_aw  = (const float*)d_in[9];
    const float* b_aw  = (const float*)d_in[10];
    const float* W_v   = (const float*)d_in[11];
    const float* b_v   = (const float*)d_in[12];
    const float* W_o   = (const float*)d_in[13];
    const float* b_o   = (const float*)d_in[14];
    const float* W_agg = (const float*)d_in[15];
    const float* b_agg = (const float*)d_in[16];
    float* out = (float*)d_out;

    float* ws = (float*)d_ws;
    float* QS0 = ws;                                        // NQ*384 fp32
    float* QS1 = QS0 + (size_t)NQ * LDQS;                   // NQ*384 fp32
    unsigned short* V0   = (unsigned short*)(QS1 + (size_t)NQ * LDQS);  // NQ*256 bf16
    unsigned short* V1   = V0 + (size_t)NQ * 256;
    unsigned short* Ocat = V1 + (size_t)NQ * 256;           // NQ*512 bf16
    unsigned short* Wvt    = Ocat + (size_t)NQ * 512;       // 65536
    unsigned short* Wsoawt = Wvt + 65536;                   // 98304
    unsigned short* Wfcat  = Wsoawt + 98304;                // 131072
    float* bsoaw = (float*)(Wfcat + 131072);                // 384
    float* bfus  = bsoaw + 384;                             // 256

    // Qb embedded in QS aw bytes (row*768+512 shorts): dead after gemm_logits
    // overwrites those bytes with normalized weights. Fb aliases Ocat (dead
    // after gemm_mid reads it; ms_sample then overwrites Ocat).
    unsigned short* Qb0 = (unsigned short*)QS0;
    unsigned short* Qb1 = (unsigned short*)QS1;
    unsigned short* Fb0 = Ocat;
    unsigned short* Fb1 = Ocat + (size_t)NQ * 256;
    const unsigned short* Qa0 = (const unsigned short*)QS0 + 512;  // A base, lda=768
    const unsigned short* Qa1 = (const unsigned short*)QS1 + 512;

    const int MB = (NQ + 127) / 128;   // 306
    dim3 blk(256);

    // 1) merged preprocessing: converts + weight prep + fused tail weights
    prep_all<<<20456, blk, 0, stream>>>(
        q0, q1, f0, f1, W_v, W_so, W_aw, b_so, b_aw, W_o, W_agg, b_o, b_agg,
        Qb0, Qb1, Fb0, Fb1, Wvt, Wsoawt, bsoaw, Wfcat, bfus);

    // 2) merged mid GEMMs: offsets (z<2) + values (z>=2) in one dispatch
    gemm_mid<<<dim3(2, MB, 4), blk, 0, stream>>>(
        Qa0, Qa1, Fb0, Fb1, Wsoawt, Wvt, bsoaw, b_v, QS0, QS1, V0, V1);

    // 3) logits + fused joint softmax -> overwrites Qb bytes with aw
    gemm_logits<<<MB, blk, 0, stream>>>(Qa0, Qa1, Wsoawt, bsoaw, QS0, QS1);

    // 4) merged sampler (both iters) -> Ocat
    ms_sample<<<2 * 2 * CHUNKS * 8, blk, 0, stream>>>(V0, V1, QS0, QS1, refp, Ocat);

    // 5) single K=512 tail GEMM -> out
    gemm_tail<<<dim3(2, MB, 1), blk, 0, stream>>>(Ocat, Wfcat, bfus, out);
}

// Round 9
// 474.172 us; speedup vs baseline: 1.1914x; 1.0123x over previous
//
#include <hip/hip_runtime.h>
#include <math.h>

#define NBATCH 2
#define LQ     19560
#define LEN    19560
#define NQ     (NBATCH * LQ)      // 39120
#define DMODEL 256
#define NHEADS 8
#define HDIM   32
#define NLEV   4
#define NPTS   4
#define LDQS   384                // QS row stride fp32: [0..255]=offsets, [256..383]=
                                  // bf16 Qb (merged mode) or raw logits (fallback)

typedef __bf16 bf16x8 __attribute__((ext_vector_type(8)));
typedef float  f32x4  __attribute__((ext_vector_type(4)));
typedef float  f32x2  __attribute__((ext_vector_type(2)));

__device__ inline unsigned short f2bf(float f) {
    unsigned int u = __float_as_uint(f);
    u += 0x7FFFu + ((u >> 16) & 1u);     // RNE
    return (unsigned short)(u >> 16);
}
// two bf16 packed in a dword -> two exact f32 (lo = u<<16, hi = u & 0xFFFF0000)
__device__ inline f32x2 bfpair(unsigned int u) {
    f32x2 r;
    r.x = __uint_as_float(u << 16);
    r.y = __uint_as_float(u & 0xFFFF0000u);
    return r;
}

// ---------------------------------------------------------------------------
// Merged preprocessing (one dispatch, disjoint outputs):
//   b in [0,19560):     fp32->bf16 convert. q0/q1 -> Qb embedded in QS aw bytes
//                       (row*768 + 512 shorts); f0/f1 -> Fb (linear, = Ocat).
//   b in [19560,20200): weight transpose/pack (Wvt, Wsoawt, bsoaw)
//   b in [20200,20456): fused tail weights Wfcat = (Wo@Wagg)^T bf16, bfused
// ---------------------------------------------------------------------------
__global__ __launch_bounds__(256) void prep_all(
    const float* __restrict__ q0, const float* __restrict__ q1,
    const float* __restrict__ f0, const float* __restrict__ f1,
    const float* __restrict__ Wv, const float* __restrict__ Wso,
    const float* __restrict__ Waw, const float* __restrict__ bso,
    const float* __restrict__ baw,
    const float* __restrict__ Wo, const float* __restrict__ Wagg,
    const float* __restrict__ bo, const float* __restrict__ bagg,
    unsigned short* __restrict__ Qb0, unsigned short* __restrict__ Qb1,
    unsigned short* __restrict__ Fb0, unsigned short* __restrict__ Fb1,
    unsigned short* __restrict__ Wvt, unsigned short* __restrict__ Wsoawt,
    float* __restrict__ bsoaw,
    unsigned short* __restrict__ Wfcat, float* __restrict__ bfused)
{
    const int b = blockIdx.x;
    if (b < 19560) {
        const int tsel = b / 4890;
        const int x = b - tsel * 4890;
        const float* s = (tsel & 2) ? ((tsel & 1) ? f1 : f0) : ((tsel & 1) ? q1 : q0);
        unsigned short* d = (tsel & 2) ? ((tsel & 1) ? Fb1 : Fb0) : ((tsel & 1) ? Qb1 : Qb0);
        size_t i = ((size_t)x * 256 + threadIdx.x) * 8;
        float4 a = *(const float4*)(s + i);
        float4 c = *(const float4*)(s + i + 4);
        union { uint4 u; unsigned short h[8]; } t;
        t.h[0] = f2bf(a.x); t.h[1] = f2bf(a.y); t.h[2] = f2bf(a.z); t.h[3] = f2bf(a.w);
        t.h[4] = f2bf(c.x); t.h[5] = f2bf(c.y); t.h[6] = f2bf(c.z); t.h[7] = f2bf(c.w);
        if (tsel & 2) {
            *(uint4*)(d + i) = t.u;                         // Fb linear
        } else {
            size_t row = i >> 8; int c8 = (int)(i & 255);   // Qb strided into QS rows
            *(uint4*)(d + row * 768 + 512 + c8) = t.u;
        }
    } else if (b < 19560 + 640) {
        int o = (b - 19560) * 256 + threadIdx.x;
        if (o < 65536) {
            int n = o >> 8, k = o & 255;
            Wvt[o] = f2bf(Wv[(size_t)k * 256 + n]);
        } else {
            int p = o - 65536;
            int n = p >> 8, k = p & 255;
            float v = (n < 256) ? Wso[(size_t)k * 256 + n] : Waw[(size_t)k * 128 + (n - 256)];
            Wsoawt[p] = f2bf(v);
        }
        if (o < 384) bsoaw[o] = (o < 256) ? bso[o] : baw[o - 256];
    } else {
        int k = b - 20200;
        int n = threadIdx.x;
        float s0 = 0.f, s1 = 0.f;
        for (int j = 0; j < 256; j++) {
            float w = Wo[k * 256 + j];
            s0 += w * Wagg[j * 256 + n];
            s1 += w * Wagg[(256 + j) * 256 + n];
        }
        Wfcat[(size_t)n * 512 + k]       = f2bf(s0);
        Wfcat[(size_t)n * 512 + 256 + k] = f2bf(s1);
        if (k == 0) {
            float bb = bagg[n];
            for (int j = 0; j < 256; j++)
                bb += bo[j] * (Wagg[j * 256 + n] + Wagg[(256 + j) * 256 + n]);
            bfused[n] = bb;
        }
    }
}

// ---------------------------------------------------------------------------
// Mega GEMM: uniform 128x128 K=256 blocks, z (+zbase) selects role:
//  z 0,1: offsets  A=Qa_z (lda 768), Bt rows 0..255,  out QS_z fp32 (ld 384)
//  z 2,3: values   A=Fb_z (lda 256), Bt=Wvt,          out V_z bf16 scatter
//  z 4,5: logits   A=Qa_z (lda 768), Bt rows 256..383, out AW_z RAW fp32
//         (x=0 only; softmax deferred to ms_sample).  All roles use the same
//         acc[4][4] (no VGPR inflation).  In merged mode z=0..5 in ONE
//         dispatch (AW disjoint from Qb -> no race); fallback launches z=4,5
//         separately after (AW aliases QS aw bytes = Qb, needs ordering).
// ---------------------------------------------------------------------------
__global__ __launch_bounds__(256) void gemm_mega(
    const unsigned short* __restrict__ Qa0, const unsigned short* __restrict__ Qa1,
    const unsigned short* __restrict__ Fb0, const unsigned short* __restrict__ Fb1,
    const unsigned short* __restrict__ Wsoawt, const unsigned short* __restrict__ Wvt,
    const float* __restrict__ bsoaw, const float* __restrict__ bv,
    float* __restrict__ QS0, float* __restrict__ QS1,
    unsigned short* __restrict__ V0, unsigned short* __restrict__ V1,
    float* __restrict__ AW0, float* __restrict__ AW1, int awld, int zbase)
{
    const int z = blockIdx.z + zbase;
    const int isVal = (z >= 2 && z < 4);
    const int isLog = (z >= 4);
    if (isLog && blockIdx.x != 0) return;
    const int zz = z & 1;

    __shared__ __align__(16) unsigned short As[128 * 64];
    __shared__ __align__(16) unsigned short Bs[128 * 64];

    const unsigned short* A = isVal ? (zz ? Fb1 : Fb0) : (zz ? Qa1 : Qa0);
    const unsigned short* Bt = isVal ? Wvt : Wsoawt;
    const float* bias = isVal ? bv : bsoaw;
    const int lda = isVal ? 256 : 768;
    const int btrow0 = isLog ? 256 : 0;
    const int bias0 = btrow0;

    const int tid  = threadIdx.x;
    const int w    = tid >> 6, lane = tid & 63;
    const int wm = w >> 1, wn = w & 1;
    const int m0 = blockIdx.y * 128, n0 = blockIdx.x * 128;
    const int lr = lane & 15, quad = lane >> 4;

    const int sr  = lane >> 3;
    const int scl = (lane & 7) ^ sr;
    const int colb = scl * 8;
    size_t arow[4], brow[4];
    #pragma unroll
    for (int j = 0; j < 4; j++) {
        int r = (w * 4 + j) * 8 + sr;
        int ra = m0 + r; if (ra > NQ - 1) ra = NQ - 1;
        arow[j] = (size_t)ra * lda;
        brow[j] = (size_t)(btrow0 + n0 + r) * 256;
    }

    const f32x4 zero = {0.f, 0.f, 0.f, 0.f};
    f32x4 acc[4][4];
    #pragma unroll
    for (int i = 0; i < 4; i++)
        #pragma unroll
        for (int j = 0; j < 4; j++) acc[i][j] = zero;

    for (int t = 0; t < 256; t += 64) {
        #pragma unroll
        for (int j = 0; j < 4; j++) {
            int lofs = __builtin_amdgcn_readfirstlane((w * 4 + j) * 1024);
            __builtin_amdgcn_global_load_lds(
                (const __attribute__((address_space(1))) void*)(A + arow[j] + t + colb),
                (__attribute__((address_space(3))) void*)((char*)As + lofs), 16, 0, 0);
            __builtin_amdgcn_global_load_lds(
                (const __attribute__((address_space(1))) void*)(Bt + brow[j] + t + colb),
                (__attribute__((address_space(3))) void*)((char*)Bs + lofs), 16, 0, 0);
        }
        __syncthreads();

        #pragma unroll
        for (int kk = 0; kk < 2; kk++) {
            bf16x8 af[4], bff[4];
            #pragma unroll
            for (int mi = 0; mi < 4; mi++) {
                int R = wm * 64 + mi * 16 + lr;
                int pc = ((kk * 4 + quad) ^ (lr & 7)) * 16;
                af[mi] = *(const bf16x8*)((const char*)As + R * 128 + pc);
            }
            #pragma unroll
            for (int ni = 0; ni < 4; ni++) {
                int R = wn * 64 + ni * 16 + lr;
                int pc = ((kk * 4 + quad) ^ (lr & 7)) * 16;
                bff[ni] = *(const bf16x8*)((const char*)Bs + R * 128 + pc);
            }
            #pragma unroll
            for (int mi = 0; mi < 4; mi++)
                #pragma unroll
                for (int ni = 0; ni < 4; ni++)
                    acc[mi][ni] = __builtin_amdgcn_mfma_f32_16x16x32_bf16(
                        af[mi], bff[ni], acc[mi][ni], 0, 0, 0);
        }
        __syncthreads();
    }

    float* Cf = isLog ? (zz ? AW1 : AW0) : (zz ? QS1 : QS0);
    const int ldc = isLog ? awld : LDQS;
    unsigned short* Cb = zz ? V1 : V0;
    #pragma unroll
    for (int mi = 0; mi < 4; mi++) {
        #pragma unroll
        for (int reg = 0; reg < 4; reg++) {
            int row = m0 + wm * 64 + mi * 16 + quad * 4 + reg;
            if (row >= NQ) continue;
            #pragma unroll
            for (int ni = 0; ni < 4; ni++) {
                int col = n0 + wn * 64 + ni * 16 + lr;
                float v = acc[mi][ni][reg] + bias[bias0 + col];
                if (!isVal) {
                    Cf[(size_t)row * ldc + col] = v;
                } else {
                    int n = row >= LQ ? 1 : 0;
                    int pos = row - n * LQ;
                    int h = col >> 5, d = col & 31;
                    Cb[((size_t)(n * NHEADS + h) * LEN + pos) * HDIM + d] = f2bf(v);
                }
            }
        }
    }
}

// ---------------------------------------------------------------------------
// Merged deformable sampling (both iters), v7:
//  - joint softmax FUSED into phase 1: lane lj loads its 8 of the 32 raw
//    logits (both iters, head h), quartet shfl_xor max/sum -> normalized aw.
//  - phase 1 stores PRE-SHIFTED u32 element offsets (idx<<5) -> phase 2 has
//    zero per-corner index math (-128 VALU/thread).
//  - gather layout unchanged: 4 lanes/query, lane owns 8 dims, dwordx4/corner.
//  LDS 33.3KB (Sidx u32 + Swt f32, [16][65][4] padded planes).
// ---------------------------------------------------------------------------
#define QCHUNK 64
#define CHUNKS ((LQ + QCHUNK - 1) / QCHUNK)   // 306

__global__ __launch_bounds__(256) void ms_sample(
    const unsigned short* __restrict__ V0, const unsigned short* __restrict__ V1,
    const float* __restrict__ QS0, const float* __restrict__ QS1,
    const float* __restrict__ AW0, const float* __restrict__ AW1, int awld,
    const float* __restrict__ refp, unsigned short* __restrict__ Ocat)
{
    __shared__ unsigned int Sidx[16][65][4];  // [plane][ql][corner] u32 elem offset
    __shared__ float        Swt [16][65][4];  // [plane][ql][corner] weight

    const int b = blockIdx.x;
    const int h = b & 7;
    const int rest = b >> 3;               // (it*2+n)*CHUNKS + chunk
    const int chunk = rest % CHUNKS;
    const int inn   = rest / CHUNKS;       // it*2 + n
    const int n  = inn & 1;
    const int it = inn >> 1;

    const int tid = threadIdx.x;
    const int ql  = tid >> 2;              // 0..63 query slot
    const int lj  = tid & 3;
    const int qraw = chunk * QCHUNK + ql;
    const bool valid = qraw < LQ;
    const int q  = valid ? qraw : LQ - 1;
    const int nq = n * LQ + q;

    const unsigned short* __restrict__ val = it ? V1 : V0;
    const float* __restrict__ QS = it ? QS1 : QS0;
    const unsigned short* __restrict__ vb2 =
        val + (size_t)(n * NHEADS + h) * LEN * HDIM;

    const int Hs[4] = {92, 46, 23, 12};
    const int Ws[4] = {160, 80, 40, 20};
    const int Ss[4] = {0, 14720, 18400, 19320};

    const float* prow = QS + (size_t)nq * LDQS;

    // ---- phase 1: joint softmax (quartet) + this lane's level (4 points) ----
    {
        // softmax over 32 = {AW0,AW1}[nq][h*16 + 0..15]; lane lj owns cols lj*4..+3
        const float4 l0 = *(const float4*)(AW0 + (size_t)nq * awld + (h << 4) + lj * 4);
        const float4 l1 = *(const float4*)(AW1 + (size_t)nq * awld + (h << 4) + lj * 4);
        float m = fmaxf(fmaxf(fmaxf(l0.x, l0.y), fmaxf(l0.z, l0.w)),
                        fmaxf(fmaxf(l1.x, l1.y), fmaxf(l1.z, l1.w)));
        m = fmaxf(m, __shfl_xor(m, 1));
        m = fmaxf(m, __shfl_xor(m, 2));
        float e0x = expf(l0.x - m), e0y = expf(l0.y - m);
        float e0z = expf(l0.z - m), e0w = expf(l0.w - m);
        float e1x = expf(l1.x - m), e1y = expf(l1.y - m);
        float e1z = expf(l1.z - m), e1w = expf(l1.w - m);
        float s = ((e0x + e0y) + (e0z + e0w)) + ((e1x + e1y) + (e1z + e1w));
        s += __shfl_xor(s, 1);
        s += __shfl_xor(s, 2);
        const float inv = 1.0f / s;
        float avs[4];
        if (it) { avs[0] = e1x * inv; avs[1] = e1y * inv; avs[2] = e1z * inv; avs[3] = e1w * inv; }
        else    { avs[0] = e0x * inv; avs[1] = e0y * inv; avs[2] = e0z * inv; avs[3] = e0w * inv; }

        const int H = Hs[lj], W = Ws[lj], S = Ss[lj];
        const float4 o0 = *(const float4*)(prow + (h << 5) + lj * 8);
        const float4 o1 = *(const float4*)(prow + (h << 5) + lj * 8 + 4);
        const float2 rp = *(const float2*)(refp + (size_t)nq * 8 + lj * 2);
        const float fx = rp.x * (float)W - 0.5f;
        const float fy = rp.y * (float)H - 0.5f;
        const float oxs[4] = {o0.x, o0.z, o1.x, o1.z};
        const float oys[4] = {o0.y, o0.w, o1.y, o1.w};
        #pragma unroll
        for (int k = 0; k < NPTS; k++) {
            const float x = fx + oxs[k];
            const float y = fy + oys[k];
            const float x0f = floorf(x), y0f = floorf(y);
            const int x0 = (int)x0f, y0 = (int)y0f;
            const float wx1 = x - x0f, wy1 = y - y0f;
            const float wx0 = 1.0f - wx1, wy0 = 1.0f - wy1;
            const int xc0 = min(max(x0, 0), W - 1);
            const int xc1 = min(max(x0 + 1, 0), W - 1);
            const int yc0 = min(max(y0, 0), H - 1);
            const int yc1 = min(max(y0 + 1, 0), H - 1);
            const float a = avs[k];
            const float ay0 = ((unsigned int)y0 < (unsigned int)H) ? a * wy0 : 0.f;
            const float ay1 = ((unsigned int)(y0 + 1) < (unsigned int)H) ? a * wy1 : 0.f;
            const float mx0 = ((unsigned int)x0 < (unsigned int)W) ? wx0 : 0.f;
            const float mx1 = ((unsigned int)(x0 + 1) < (unsigned int)W) ? wx1 : 0.f;
            const int r0 = S + yc0 * W, r1 = S + yc1 * W;
            uint4 eo4;
            eo4.x = (unsigned int)(r0 + xc0) << 5;
            eo4.y = (unsigned int)(r0 + xc1) << 5;
            eo4.z = (unsigned int)(r1 + xc0) << 5;
            eo4.w = (unsigned int)(r1 + xc1) << 5;
            *(uint4*)&Sidx[lj * 4 + k][ql][0] = eo4;
            float4 w4 = make_float4(ay0 * mx0, ay0 * mx1, ay1 * mx0, ay1 * mx1);
            *(float4*)&Swt[lj * 4 + k][ql][0] = w4;
        }
    }
    __syncthreads();

    // ---- phase 2: gather all 16 staged points (zero index math) ----
    const int dl = lj << 3;                // dim quarter 0,8,16,24
    const unsigned short* __restrict__ vdl = vb2 + dl;

    f32x2 acc[4];
    #pragma unroll
    for (int i = 0; i < 4; i++) acc[i] = (f32x2){0.f, 0.f};

    auto corner = [&](unsigned int eo, float wgt) {
        const uint4 c = *(const uint4*)(vdl + eo);
        const f32x2 w2 = {wgt, wgt};
        acc[0] += w2 * bfpair(c.x);
        acc[1] += w2 * bfpair(c.y);
        acc[2] += w2 * bfpair(c.z);
        acc[3] += w2 * bfpair(c.w);
    };

    #pragma unroll
    for (int p = 0; p < 16; p++) {
        const uint4 i4 = *(const uint4*)&Sidx[p][ql][0];
        const float4 w4 = *(const float4*)&Swt[p][ql][0];
        corner(i4.x, w4.x);
        corner(i4.y, w4.y);
        corner(i4.z, w4.z);
        corner(i4.w, w4.w);
    }

    if (valid) {
        union { uint4 u; unsigned short s[8]; } t;
        #pragma unroll
        for (int i = 0; i < 4; i++) {
            t.s[2 * i]     = f2bf(acc[i].x);
            t.s[2 * i + 1] = f2bf(acc[i].y);
        }
        *(uint4*)&Ocat[(size_t)nq * 512 + it * 256 + h * HDIM + dl] = t.u;
    }
}

// ---------------------------------------------------------------------------
// Tail GEMM: C = Ocat @ Wfcat^T + bfused, fp32 out. K=512.
// ---------------------------------------------------------------------------
__global__ __launch_bounds__(256) void gemm_tail(
    const unsigned short* __restrict__ A, const unsigned short* __restrict__ Bt,
    const float* __restrict__ bias, float* __restrict__ C)
{
    __shared__ __align__(16) unsigned short As[128 * 64];
    __shared__ __align__(16) unsigned short Bs[128 * 64];

    const int tid  = threadIdx.x;
    const int w    = tid >> 6, lane = tid & 63;
    const int wm = w >> 1, wn = w & 1;
    const int m0 = blockIdx.y * 128, n0 = blockIdx.x * 128;
    const int lr = lane & 15, quad = lane >> 4;

    const int sr  = lane >> 3;
    const int scl = (lane & 7) ^ sr;
    const int colb = scl * 8;
    size_t arow[4], brow[4];
    #pragma unroll
    for (int j = 0; j < 4; j++) {
        int r = (w * 4 + j) * 8 + sr;
        int ra = m0 + r; if (ra > NQ - 1) ra = NQ - 1;
        arow[j] = (size_t)ra * 512;
        brow[j] = (size_t)(n0 + r) * 512;
    }

    const f32x4 zero = {0.f, 0.f, 0.f, 0.f};
    f32x4 acc[4][4];
    #pragma unroll
    for (int i = 0; i < 4; i++)
        #pragma unroll
        for (int j = 0; j < 4; j++) acc[i][j] = zero;

    for (int t = 0; t < 512; t += 64) {
        #pragma unroll
        for (int j = 0; j < 4; j++) {
            int lofs = __builtin_amdgcn_readfirstlane((w * 4 + j) * 1024);
            __builtin_amdgcn_global_load_lds(
                (const __attribute__((address_space(1))) void*)(A + arow[j] + t + colb),
                (__attribute__((address_space(3))) void*)((char*)As + lofs), 16, 0, 0);
            __builtin_amdgcn_global_load_lds(
                (const __attribute__((address_space(1))) void*)(Bt + brow[j] + t + colb),
                (__attribute__((address_space(3))) void*)((char*)Bs + lofs), 16, 0, 0);
        }
        __syncthreads();

        #pragma unroll
        for (int kk = 0; kk < 2; kk++) {
            bf16x8 af[4], bff[4];
            #pragma unroll
            for (int mi = 0; mi < 4; mi++) {
                int R = wm * 64 + mi * 16 + lr;
                int pc = ((kk * 4 + quad) ^ (lr & 7)) * 16;
                af[mi] = *(const bf16x8*)((const char*)As + R * 128 + pc);
            }
            #pragma unroll
            for (int ni = 0; ni < 4; ni++) {
                int R = wn * 64 + ni * 16 + lr;
                int pc = ((kk * 4 + quad) ^ (lr & 7)) * 16;
                bff[ni] = *(const bf16x8*)((const char*)Bs + R * 128 + pc);
            }
            #pragma unroll
            for (int mi = 0; mi < 4; mi++)
                #pragma unroll
                for (int ni = 0; ni < 4; ni++)
                    acc[mi][ni] = __builtin_amdgcn_mfma_f32_16x16x32_bf16(
                        af[mi], bff[ni], acc[mi][ni], 0, 0, 0);
        }
        __syncthreads();
    }

    #pragma unroll
    for (int mi = 0; mi < 4; mi++) {
        #pragma unroll
        for (int reg = 0; reg < 4; reg++) {
            int row = m0 + wm * 64 + mi * 16 + quad * 4 + reg;
            if (row >= NQ) continue;
            #pragma unroll
            for (int ni = 0; ni < 4; ni++) {
                int col = n0 + wn * 64 + ni * 16 + lr;
                C[(size_t)row * 256 + col] = acc[mi][ni][reg] + bias[col];
            }
        }
    }
}

// ---------------------------------------------------------------------------
extern "C" void kernel_launch(void* const* d_in, const int* in_sizes, int n_in,
                              void* d_out, int out_size, void* d_ws, size_t ws_size,
                              hipStream_t stream)
{
    const float* q0    = (const float*)d_in[0];
    const float* q1    = (const float*)d_in[1];
    const float* refp  = (const float*)d_in[2];
    const float* f0    = (const float*)d_in[3];
    const float* f1    = (const float*)d_in[4];
    const float* W_so  = (const float*)d_in[7];
    const float* b_so  = (const float*)d_in[8];
    const float* W_aw  = (const float*)d_in[9];
    const float* b_aw  = (const float*)d_in[10];
    const float* W_v   = (const float*)d_in[11];
    const float* b_v   = (const float*)d_in[12];
    const float* W_o   = (const float*)d_in[13];
    const float* b_o   = (const float*)d_in[14];
    const float* W_agg = (const float*)d_in[15];
    const float* b_agg = (const float*)d_in[16];
    float* out = (float*)d_out;

    float* ws = (float*)d_ws;
    float* QS0 = ws;                                        // NQ*384 fp32
    float* QS1 = QS0 + (size_t)NQ * LDQS;                   // NQ*384 fp32
    unsigned short* V0   = (unsigned short*)(QS1 + (size_t)NQ * LDQS);  // NQ*256 bf16
    unsigned short* V1   = V0 + (size_t)NQ * 256;
    unsigned short* Ocat = V1 + (size_t)NQ * 256;           // NQ*512 bf16
    unsigned short* Wvt    = Ocat + (size_t)NQ * 512;       // 65536
    unsigned short* Wsoawt = Wvt + 65536;                   // 98304
    unsigned short* Wfcat  = Wsoawt + 98304;                // 131072
    float* bsoaw = (float*)(Wfcat + 131072);                // 384
    float* bfus  = bsoaw + 384;                             // 256
    float* wsend = bfus + 256;

    // Qb embedded in QS aw bytes (row*768+512 shorts). Fb aliases Ocat (dead
    // after mega reads it; ms_sample then overwrites Ocat).
    unsigned short* Qb0 = (unsigned short*)QS0;
    unsigned short* Qb1 = (unsigned short*)QS1;
    unsigned short* Fb0 = Ocat;
    unsigned short* Fb1 = Ocat + (size_t)NQ * 256;
    const unsigned short* Qa0 = (const unsigned short*)QS0 + 512;  // A base, lda=768
    const unsigned short* Qa1 = (const unsigned short*)QS1 + 512;

    // Raw-logit buffer: separate AW region if workspace allows (merged mode:
    // mega computes logits concurrently — AW disjoint from Qb, no race).
    // Fallback: AW aliases QS aw bytes (over Qb) and logits run as a separate
    // dispatch AFTER mega (stream order protects the Qb reads).
    size_t aw_bytes = (size_t)NQ * 128 * 4 * 2;
    size_t need_merged = ((size_t)((char*)wsend - (char*)ws)) + aw_bytes;
    const int merged = ws_size >= need_merged;
    float *AW0, *AW1;
    int awld;
    if (merged) {
        AW0 = wsend;
        AW1 = AW0 + (size_t)NQ * 128;
        awld = 128;
    } else {
        AW0 = QS0 + 256;
        AW1 = QS1 + 256;
        awld = LDQS;
    }

    const int MB = (NQ + 127) / 128;   // 306
    dim3 blk(256);

    // 1) merged preprocessing: converts + weight prep + fused tail weights
    prep_all<<<20456, blk, 0, stream>>>(
        q0, q1, f0, f1, W_v, W_so, W_aw, b_so, b_aw, W_o, W_agg, b_o, b_agg,
        Qb0, Qb1, Fb0, Fb1, Wvt, Wsoawt, bsoaw, Wfcat, bfus);

    // 2) mega GEMM: offsets + values (+ raw logits when merged)
    if (merged) {
        gemm_mega<<<dim3(2, MB, 6), blk, 0, stream>>>(
            Qa0, Qa1, Fb0, Fb1, Wsoawt, Wvt, bsoaw, b_v,
            QS0, QS1, V0, V1, AW0, AW1, awld, 0);
    } else {
        gemm_mega<<<dim3(2, MB, 4), blk, 0, stream>>>(
            Qa0, Qa1, Fb0, Fb1, Wsoawt, Wvt, bsoaw, b_v,
            QS0, QS1, V0, V1, AW0, AW1, awld, 0);
        gemm_mega<<<dim3(1, MB, 2), blk, 0, stream>>>(
            Qa0, Qa1, Fb0, Fb1, Wsoawt, Wvt, bsoaw, b_v,
            QS0, QS1, V0, V1, AW0, AW1, awld, 4);
    }

    // 3) merged sampler (both iters, fused joint softmax) -> Ocat
    ms_sample<<<2 * 2 * CHUNKS * 8, blk, 0, stream>>>(
        V0, V1, QS0, QS1, AW0, AW1, awld, refp, Ocat);

    // 4) single K=512 tail GEMM -> out
    gemm_tail<<<dim3(2, MB, 1), blk, 0, stream>>>(Ocat, Wfcat, bfus, out);
}